// Round 16
// baseline (344.818 us; speedup 1.0000x reference)
//
#include <hip/hip_runtime.h>
#include <hip/hip_bf16.h>

// MultiheadAttention_ViTNO: B=8, P=256, S=8x8(=64), D=256, NHEAD=8, DK=32, SCALE=64
// R16: revert tail to R12 (R15's double-change regressed 25us). Structural win:
// k2t DELETED. k1 re-tiled over (b, sxy, p-block-64) so each tile holds 64
// consecutive q=p values; V epilogue transposes in LDS (R14-proven pattern,
// XOR pl^8*(ip&7)) and stores directly in Vq[bn][c][q] layout -> k2t's 134MB
// + launch removed. Q/K stores unchanged quality (k=sxy*32+dk, sxy const/tile).
// k0/k2a/k2b/k3 = R12 verbatim.

typedef __bf16 bf16;
typedef __attribute__((ext_vector_type(8))) __bf16 bf16x8;
typedef __attribute__((ext_vector_type(4))) float floatx4;
typedef __attribute__((ext_vector_type(8))) unsigned short ushort8;

#define CDIM 2048             // 64*32 flattened (sxy, dk) per head

static __device__ __forceinline__ floatx4 mfma16(bf16x8 a, bf16x8 b, floatx4 c) {
  return __builtin_amdgcn_mfma_f32_16x16x32_bf16(a, b, c, 0, 0, 0);
}

static __device__ __forceinline__ void gload_lds16(const void* g, void* l) {
  __builtin_amdgcn_global_load_lds((const __attribute__((address_space(1))) void*)g,
                                   (__attribute__((address_space(3))) void*)l, 16, 0, 0);
}

// ---------------- K0: weight prep (unchanged) ----------------
__global__ __launch_bounds__(256) void k0_prep(
    const float* __restrict__ Wq, const float* __restrict__ bq,
    const float* __restrict__ Wk, const float* __restrict__ bk,
    const float* __restrict__ Wv, const float* __restrict__ bv,
    const float* __restrict__ Wo,
    bf16* __restrict__ Wp, bf16* __restrict__ Wk3, float* __restrict__ biasp)
{
  const int bid = blockIdx.x, tid = threadIdx.x;
  int g = (bid & 31) * 256 + tid;       // 0..8191 : (kk, rowblk, lane)
  int lane = g & 63, rowblk = (g >> 6) & 15, kk = g >> 10;
  int h = lane >> 4, cl = lane & 15;
  int d0 = kk * 32 + 8 * h;
  if (bid < 32) {
    int ip = rowblk * 16 + cl;          // i' = n*32+dk
    int isrc = ((ip & 31) << 3) | (ip >> 5);
#pragma unroll
    for (int mat = 0; mat < 3; mat++) {
      const float* W = (mat == 0) ? Wq : (mat == 1) ? Wk : Wv;
      bf16x8 v;
#pragma unroll
      for (int j = 0; j < 8; j++) v[j] = (bf16)W[isrc * 256 + d0 + j];
      *reinterpret_cast<bf16x8*>(Wp + ((size_t)mat * 8192 + g) * 8) = v;
    }
    if (bid == 0 && tid < 256) {
      int bs = ((tid & 31) << 3) | (tid >> 5);
      biasp[tid] = bq[bs]; biasp[256 + tid] = bk[bs]; biasp[512 + tid] = bv[bs];
    }
  } else {
    int j = rowblk * 16 + cl;           // output col
    bf16x8 v;
#pragma unroll
    for (int jj = 0; jj < 8; jj++) {
      int c = d0 + jj;
      v[jj] = (bf16)Wo[j * 256 + (((c & 31) << 3) | (c >> 5))];
    }
    *reinterpret_cast<bf16x8*>(Wk3 + (size_t)g * 8) = v;
  }
}

// ---------------- K1: fused QKV projection, (b,sxy,pblk) tiles ----------------
// grid 1536; block 512 (8 waves); 4 units/block, vb = bx + 1536*u.
// Decode: a=vb/24, rem=vb%24, mat=rem>>3, tile=a*8+(rem&7) in [0,2048);
//   b=tile>>8, sxy=(tile>>2)&63, pblk=tile&3. Row r of tile = p-local index:
//   t = (b*256 + pblk*64 + r)*64 + sxy. Q/K -> scores layout direct store;
//   V -> LDS transpose -> Vq[bn][c][q] (k2t eliminated).
__global__ __launch_bounds__(512, 4) void k1_qkv(
    const float* __restrict__ x, const bf16* __restrict__ Wp,
    const float* __restrict__ biasp,
    bf16* __restrict__ Qs, bf16* __restrict__ Ks, bf16* __restrict__ Vq)
{
  __shared__ bf16 buf[2][64 * 256];     // 2 x 32KB, granule-XOR-swizzled
  const int bx = blockIdx.x;
  const int tid = threadIdx.x;
  const int lane = tid & 63;
  const int w = tid >> 6;               // wave 0..7 -> ip slice [w*32, w*32+32)
  const int h = lane >> 4, cl = lane & 15;
  const int c7 = cl & 7;

  floatx4 sreg[8];                      // staging regs (one 64-row tile)
  floatx4 acc[4][2];                    // live across epilogue barriers

#define K1_DEC(VB)                                                           \
    int a_ = (VB) / 24;                                                      \
    int rem_ = (VB) - a_ * 24;                                               \
    int mat_ = rem_ >> 3;                                                    \
    int tile_ = a_ * 8 + (rem_ & 7);                                         \
    int b_ = tile_ >> 8, sxy_ = (tile_ >> 2) & 63, pblk_ = tile_ & 3;        \
    (void)mat_; (void)b_; (void)sxy_; (void)pblk_;

#define K1_LOAD(VB)                                                          \
  {                                                                          \
    K1_DEC(VB)                                                               \
    _Pragma("unroll")                                                        \
    for (int k = 0; k < 4; ++k) {                                            \
      int G = k * 512 + tid;                                                 \
      int row = G >> 5;                                                      \
      const float* sp = x +                                                  \
          (size_t)((b_ * 256 + pblk_ * 64 + row) * 64 + sxy_) * 256 + (G & 31) * 8; \
      sreg[2 * k]     = *reinterpret_cast<const floatx4*>(sp);               \
      sreg[2 * k + 1] = *reinterpret_cast<const floatx4*>(sp + 4);           \
    }                                                                        \
  }

#define K1_CVTWRITE(BUFI)                                                    \
  {                                                                          \
    _Pragma("unroll")                                                        \
    for (int k = 0; k < 4; ++k) {                                            \
      int G = k * 512 + tid;                                                 \
      int row = G >> 5;                                                      \
      bf16x8 v;                                                              \
      _Pragma("unroll")                                                      \
      for (int j = 0; j < 4; j++) {                                          \
        v[j] = (bf16)sreg[2 * k][j];                                         \
        v[4 + j] = (bf16)sreg[2 * k + 1][j];                                 \
      }                                                                      \
      int Gp = (G & ~7) | ((G ^ row) & 7);                                   \
      *reinterpret_cast<bf16x8*>(&buf[BUFI][Gp * 8]) = v;                    \
    }                                                                        \
  }

// compute acc; Q/K stored directly (32B segments); V kept in acc for epilogue
#define K1_COMPUTE(VB, BUFI)                                                 \
  {                                                                          \
    K1_DEC(VB)                                                               \
    const bf16* Wm = Wp + (size_t)mat_ * 65536;                              \
    _Pragma("unroll")                                                        \
    for (int i = 0; i < 4; i++)                                              \
      _Pragma("unroll")                                                      \
      for (int j = 0; j < 2; j++) acc[i][j] = (floatx4)0.0f;                 \
    _Pragma("unroll 2")                                                      \
    for (int kk = 0; kk < 8; ++kk) {                                         \
      bf16x8 av[4];                                                          \
      _Pragma("unroll")                                                      \
      for (int mt = 0; mt < 4; mt++) {                                       \
        int rr = mt * 16 + cl;                                               \
        int G = rr * 32 + kk * 4 + h;                                        \
        int Gp = (G & ~7) | ((G ^ c7) & 7);                                  \
        av[mt] = *reinterpret_cast<const bf16x8*>(&buf[BUFI][Gp * 8]);       \
      }                                                                      \
      bf16x8 b0 = *reinterpret_cast<const bf16x8*>(                          \
          Wm + ((size_t)(kk * 16 + w * 2 + 0) * 64 + lane) * 8);             \
      bf16x8 b1 = *reinterpret_cast<const bf16x8*>(                          \
          Wm + ((size_t)(kk * 16 + w * 2 + 1) * 64 + lane) * 8);             \
      _Pragma("unroll")                                                      \
      for (int mt = 0; mt < 4; mt++) acc[mt][0] = mfma16(av[mt], b0, acc[mt][0]); \
      _Pragma("unroll")                                                      \
      for (int mt = 0; mt < 4; mt++) acc[mt][1] = mfma16(av[mt], b1, acc[mt][1]); \
    }                                                                        \
    if (mat_ < 2) {                                                          \
      bf16* ob = ((mat_ == 0) ? Qs : Ks) + (size_t)(b_ * 8 + w) * 524288;    \
      _Pragma("unroll")                                                      \
      for (int nt = 0; nt < 2; nt++) {                                       \
        const float bb = biasp[mat_ * 256 + w * 32 + nt * 16 + cl];          \
        const int dk = nt * 16 + cl;                                         \
        _Pragma("unroll")                                                    \
        for (int mt = 0; mt < 4; mt++)                                       \
          _Pragma("unroll")                                                  \
          for (int r = 0; r < 4; r++) {                                      \
            int pl = mt * 16 + 4 * h + r;                                    \
            ob[(size_t)(pblk_ * 64 + pl) * 2048 + sxy_ * 32 + dk]            \
                = (bf16)(acc[mt][nt][r] + bb);                               \
          }                                                                  \
      }                                                                      \
    }                                                                        \
  }

// V only: acc(+bias) -> LDS transposed [ip][pl], XOR pl^(8*(ip&7))
#define K1_V_EPI_LDS(VB, BUFI)                                               \
  {                                                                          \
    K1_DEC(VB)                                                               \
    if (mat_ == 2) {                                                         \
      _Pragma("unroll")                                                      \
      for (int nt = 0; nt < 2; nt++) {                                       \
        const int ip = w * 32 + nt * 16 + cl;                                \
        const float bb = biasp[512 + ip];                                    \
        const int sx = 8 * (ip & 7);                                         \
        _Pragma("unroll")                                                    \
        for (int mt = 0; mt < 4; mt++)                                       \
          _Pragma("unroll")                                                  \
          for (int r = 0; r < 4; r++) {                                      \
            int pl = mt * 16 + 4 * h + r;                                    \
            buf[BUFI][ip * 64 + (pl ^ sx)] = (bf16)(acc[mt][nt][r] + bb);    \
          }                                                                  \
      }                                                                      \
    }                                                                        \
  }

// V only: LDS -> Vq[bn][c=sxy*32+dk][q=pblk*64+pl], 16B/thread, 128B segments
#define K1_V_EPI_STORE(VB, BUFI)                                             \
  {                                                                          \
    K1_DEC(VB)                                                               \
    if (mat_ == 2) {                                                         \
      _Pragma("unroll")                                                      \
      for (int j = 0; j < 4; ++j) {                                          \
        int ip_ = j * 64 + (tid >> 3);                                       \
        int c8 = tid & 7;                                                    \
        int pb = c8 ^ (ip_ & 7);                                             \
        ushort8 v = *reinterpret_cast<const ushort8*>(                       \
            &buf[BUFI][ip_ * 64 + pb * 8]);                                  \
        int n_ = ip_ >> 5, dk_ = ip_ & 31;                                   \
        *reinterpret_cast<ushort8*>(Vq + (size_t)(b_ * 8 + n_) * 524288      \
            + (size_t)(sxy_ * 32 + dk_) * 256 + pblk_ * 64 + c8 * 8) = v;    \
      }                                                                      \
    }                                                                        \
  }

  K1_LOAD(bx);
  K1_CVTWRITE(0);
  __syncthreads();
#pragma unroll
  for (int u = 1; u < 4; ++u) {
    K1_LOAD(bx + u * 1536);
    K1_COMPUTE(bx + (u - 1) * 1536, (u - 1) & 1);
    __syncthreads();                    // buf[(u-1)&1] reads done
    K1_V_EPI_LDS(bx + (u - 1) * 1536, (u - 1) & 1);
    K1_CVTWRITE(u & 1);                 // other buffer: safe concurrently
    __syncthreads();                    // epi tile + next tile published
    K1_V_EPI_STORE(bx + (u - 1) * 1536, (u - 1) & 1);
  }
  K1_COMPUTE(bx + 3 * 1536, 1);
  __syncthreads();
  K1_V_EPI_LDS(bx + 3 * 1536, 1);
  __syncthreads();
  K1_V_EPI_STORE(bx + 3 * 1536, 1);

#undef K1_DEC
#undef K1_LOAD
#undef K1_CVTWRITE
#undef K1_COMPUTE
#undef K1_V_EPI_LDS
#undef K1_V_EPI_STORE
}

// ---------------- K2a: scores + softmax (counted-vmcnt, triple-buffer, R12) ----
__global__ __launch_bounds__(1024, 1) void k2a_scores(
    const bf16* __restrict__ Qs, const bf16* __restrict__ Ks,
    bf16* __restrict__ attn)
{
  __shared__ bf16 Qch[3][128 * 64];     // 16KB x3
  __shared__ bf16 Kch[3][256 * 64];     // 32KB x3 (total 144KB)
  __shared__ float redmax[4][4][32];
  __shared__ float redsum[4][4][32];

  const int bx = blockIdx.x;
  const int bn = bx & 63;
  const int p0 = (bx >> 6) * 128;
  const int tid = threadIdx.x;
  const int lane = tid & 63;
  const int w = tid >> 6;               // 0..15
  const int wr = w >> 2, wc = w & 3;
  const int h = lane >> 4, cl = lane & 15;

  const bf16* Qb = Qs + (size_t)bn * 524288 + (size_t)p0 * 2048;
  const bf16* Kb = Ks + (size_t)bn * 524288;

  const int Lq = w * 64 + lane;
  const int rq = Lq >> 3, sq = (Lq & 7) ^ (rq & 7);
  const size_t qsrc = (size_t)rq * 2048 + sq * 8;
  int rk[2]; size_t ksrc[2];
#pragma unroll
  for (int i = 0; i < 2; ++i) {
    int L = i * 1024 + w * 64 + lane;
    rk[i] = L >> 3;
    int s = (L & 7) ^ (rk[i] & 7);
    ksrc[i] = (size_t)rk[i] * 2048 + s * 8;
  }

#define K2A_STAGE(bufi, c)                                                  \
  {                                                                         \
    gload_lds16(Qb + qsrc + (c) * 64, &Qch[bufi][(w * 64) * 8]);            \
    gload_lds16(Kb + ksrc[0] + (c) * 64, &Kch[bufi][(w * 64) * 8]);         \
    gload_lds16(Kb + ksrc[1] + (c) * 64, &Kch[bufi][(1024 + w * 64) * 8]);  \
  }

  floatx4 acc[2][4];
#pragma unroll
  for (int i = 0; i < 2; i++)
#pragma unroll
    for (int j = 0; j < 4; j++) acc[i][j] = (floatx4)0.0f;

  K2A_STAGE(0, 0);
  K2A_STAGE(1, 1);
  asm volatile("s_waitcnt vmcnt(3)" ::: "memory");
  __builtin_amdgcn_s_barrier();
  __builtin_amdgcn_sched_barrier(0);

  for (int c = 0; c < 32; ++c) {
    const int cur = c % 3;
    if (c + 2 < 32) { const int nb = (c + 2) % 3; K2A_STAGE(nb, c + 2); }
#pragma unroll
    for (int kk = 0; kk < 2; ++kk) {
      bf16x8 av[2], bv[4];
#pragma unroll
      for (int mt = 0; mt < 2; mt++) {
        int row = wr * 32 + mt * 16 + cl;
        int gg = kk * 4 + h;
        av[mt] = *reinterpret_cast<const bf16x8*>(
            &Qch[cur][(row * 8 + (gg ^ (row & 7))) * 8]);
      }
#pragma unroll
      for (int nt = 0; nt < 4; nt++) {
        int row = wc * 64 + nt * 16 + cl;
        int gg = kk * 4 + h;
        bv[nt] = *reinterpret_cast<const bf16x8*>(
            &Kch[cur][(row * 8 + (gg ^ (row & 7))) * 8]);
      }
#pragma unroll
      for (int nt = 0; nt < 4; nt++)
#pragma unroll
        for (int mt = 0; mt < 2; mt++)
          acc[mt][nt] = mfma16(av[mt], bv[nt], acc[mt][nt]);
    }
    if (c + 2 < 32) asm volatile("s_waitcnt vmcnt(3)" ::: "memory");
    else            asm volatile("s_waitcnt vmcnt(0)" ::: "memory");
    __builtin_amdgcn_s_barrier();
    __builtin_amdgcn_sched_barrier(0);
  }

  float pm[2][4];
#pragma unroll
  for (int mt = 0; mt < 2; mt++)
#pragma unroll
    for (int r = 0; r < 4; r++)
      pm[mt][r] = fmaxf(fmaxf(acc[mt][0][r], acc[mt][1][r]),
                        fmaxf(acc[mt][2][r], acc[mt][3][r]));
#pragma unroll
  for (int off = 1; off < 16; off <<= 1)
#pragma unroll
    for (int mt = 0; mt < 2; mt++)
#pragma unroll
      for (int r = 0; r < 4; r++)
        pm[mt][r] = fmaxf(pm[mt][r], __shfl_xor(pm[mt][r], off, 64));
  if (cl == 0) {
#pragma unroll
    for (int mt = 0; mt < 2; mt++)
#pragma unroll
      for (int r = 0; r < 4; r++) redmax[wr][wc][mt * 16 + 4 * h + r] = pm[mt][r];
  }
  __syncthreads();

  float gm[2][4], ps[2][4];
#pragma unroll
  for (int mt = 0; mt < 2; mt++)
#pragma unroll
    for (int r = 0; r < 4; r++) {
      int row = mt * 16 + 4 * h + r;
      gm[mt][r] = fmaxf(fmaxf(redmax[wr][0][row], redmax[wr][1][row]),
                        fmaxf(redmax[wr][2][row], redmax[wr][3][row]));
      ps[mt][r] = 0.0f;
    }
  const float KS = 1.44269504088896340736f / 64.0f;   // log2(e)/SCALE
#pragma unroll
  for (int mt = 0; mt < 2; mt++)
#pragma unroll
    for (int nt = 0; nt < 4; nt++)
#pragma unroll
      for (int r = 0; r < 4; r++) {
        float e = exp2f((acc[mt][nt][r] - gm[mt][r]) * KS);
        acc[mt][nt][r] = e;
        ps[mt][r] += e;
      }
#pragma unroll
  for (int off = 1; off < 16; off <<= 1)
#pragma unroll
    for (int mt = 0; mt < 2; mt++)
#pragma unroll
      for (int r = 0; r < 4; r++) ps[mt][r] += __shfl_xor(ps[mt][r], off, 64);
  if (cl == 0) {
#pragma unroll
    for (int mt = 0; mt < 2; mt++)
#pragma unroll
      for (int r = 0; r < 4; r++) redsum[wr][wc][mt * 16 + 4 * h + r] = ps[mt][r];
  }
  __syncthreads();

#pragma unroll
  for (int mt = 0; mt < 2; mt++)
#pragma unroll
    for (int r = 0; r < 4; r++) {
      int row = mt * 16 + 4 * h + r;
      float gs = (redsum[wr][0][row] + redsum[wr][1][row])
               + (redsum[wr][2][row] + redsum[wr][3][row]);
      ps[mt][r] = 1.0f / gs;
    }
#pragma unroll
  for (int nt = 0; nt < 4; nt++) {
    int q = wc * 64 + nt * 16 + cl;
#pragma unroll
    for (int mt = 0; mt < 2; mt++)
#pragma unroll
      for (int r = 0; r < 4; r++) {
        int row = p0 + wr * 32 + mt * 16 + 4 * h + r;
        attn[(size_t)bn * 65536 + row * 256 + q] = (bf16)(acc[mt][nt][r] * ps[mt][r]);
      }
  }
#undef K2A_STAGE
}

// ---------------- K2b: O = attn @ V (R12 verbatim) ----------------
__global__ __launch_bounds__(512, 6) void k2b_pv(
    const bf16* __restrict__ attn, const bf16* __restrict__ Vq,
    bf16* __restrict__ yhat)
{
  __shared__ bf16 As[64 * 256];         // 32KB
  const int bx = blockIdx.x;
  const int bn = bx & 63;
  const int r2 = bx >> 6;               // 0..31
  const int p0 = (r2 & 3) * 64;
  const int c0 = (r2 >> 2) * 256;
  const int b = bn >> 3, n = bn & 7;
  const int tid = threadIdx.x;
  const int lane = tid & 63;
  const int w = tid >> 6;               // wave -> 32-c slice of ctile
  const int h = lane >> 4, cl = lane & 15;
  const int c7 = cl & 7;

  const bf16* Ab = attn + (size_t)bn * 65536 + (size_t)p0 * 256;
  const bf16* Vb = Vq + (size_t)bn * 524288;

#pragma unroll
  for (int i = 0; i < 4; ++i) {
    int L = (i * 8 + w) * 64 + lane;
    int S = (L & ~7) | ((L ^ (L >> 5)) & 7);
    gload_lds16(Ab + (size_t)S * 8, &As[(size_t)(i * 8 + w) * 64 * 8]);
  }
  __syncthreads();

  floatx4 acc[4][2];
#pragma unroll
  for (int i = 0; i < 4; i++)
#pragma unroll
    for (int j = 0; j < 2; j++) acc[i][j] = (floatx4)0.0f;

#pragma unroll 2
  for (int kk = 0; kk < 8; ++kk) {
    bf16x8 av[4];
#pragma unroll
    for (int mt = 0; mt < 4; mt++) {
      int rr = mt * 16 + cl;
      int G = rr * 32 + kk * 4 + h;
      int Gp = (G & ~7) | ((G ^ c7) & 7);
      av[mt] = *reinterpret_cast<const bf16x8*>(&As[Gp * 8]);
    }
    bf16x8 b0 = *reinterpret_cast<const bf16x8*>(
        Vb + (size_t)(c0 + w * 32 + cl) * 256 + kk * 32 + 8 * h);
    bf16x8 b1 = *reinterpret_cast<const bf16x8*>(
        Vb + (size_t)(c0 + w * 32 + 16 + cl) * 256 + kk * 32 + 8 * h);
#pragma unroll
    for (int mt = 0; mt < 4; mt++) acc[mt][0] = mfma16(av[mt], b0, acc[mt][0]);
#pragma unroll
    for (int mt = 0; mt < 4; mt++) acc[mt][1] = mfma16(av[mt], b1, acc[mt][1]);
  }

#pragma unroll
  for (int nt = 0; nt < 2; nt++) {
    const int cg = c0 + w * 32 + nt * 16 + cl;
    const int dk = cg & 31, sxy = cg >> 5;
#pragma unroll
    for (int mt = 0; mt < 4; mt++)
#pragma unroll
      for (int r = 0; r < 4; r++) {
        int p = p0 + mt * 16 + 4 * h + r;
        size_t t = (size_t)((b * 256 + p) * 64) + sxy;
        yhat[t * 256 + n * 32 + dk] = (bf16)acc[mt][nt][r];
      }
  }
}

// ---------------- K3: output projection (R12 verbatim) ----------------
__global__ __launch_bounds__(512, 6) void k3_out(
    const bf16* __restrict__ yhat, const bf16* __restrict__ Wk3,
    const float* __restrict__ bo, float* __restrict__ outp)
{
  __shared__ bf16 As[64 * 256];         // 32KB
  const int t0 = blockIdx.x * 64;
  const int tid = threadIdx.x;
  const int lane = tid & 63;
  const int w = tid >> 6;
  const int h = lane >> 4, cl = lane & 15;
  const int c7 = cl & 7;

  const bf16* Ab = yhat + (size_t)t0 * 256;

#pragma unroll
  for (int i = 0; i < 4; ++i) {
    int L = (i * 8 + w) * 64 + lane;
    int S = (L & ~7) | ((L ^ (L >> 5)) & 7);
    gload_lds16(Ab + (size_t)S * 8, &As[(size_t)(i * 8 + w) * 64 * 8]);
  }
  __syncthreads();

  floatx4 acc[4][2];
#pragma unroll
  for (int i = 0; i < 4; i++)
#pragma unroll
    for (int j = 0; j < 2; j++) acc[i][j] = (floatx4)0.0f;

#pragma unroll 2
  for (int kk = 0; kk < 8; ++kk) {
    bf16x8 av[4];
#pragma unroll
    for (int mt = 0; mt < 4; mt++) {
      int rr = mt * 16 + cl;
      int G = rr * 32 + kk * 4 + h;
      int Gp = (G & ~7) | ((G ^ c7) & 7);
      av[mt] = *reinterpret_cast<const bf16x8*>(&As[Gp * 8]);
    }
    bf16x8 b0 = *reinterpret_cast<const bf16x8*>(
        Wk3 + ((size_t)(kk * 16 + w * 2 + 0) * 64 + lane) * 8);
    bf16x8 b1 = *reinterpret_cast<const bf16x8*>(
        Wk3 + ((size_t)(kk * 16 + w * 2 + 1) * 64 + lane) * 8);
#pragma unroll
    for (int mt = 0; mt < 4; mt++) acc[mt][0] = mfma16(av[mt], b0, acc[mt][0]);
#pragma unroll
    for (int mt = 0; mt < 4; mt++) acc[mt][1] = mfma16(av[mt], b1, acc[mt][1]);
  }

#pragma unroll
  for (int nt = 0; nt < 2; nt++) {
    const int j = w * 32 + nt * 16 + cl;
    const float bb = bo[j];
#pragma unroll
    for (int mt = 0; mt < 4; mt++)
#pragma unroll
      for (int r = 0; r < 4; r++)
        outp[(size_t)(t0 + mt * 16 + 4 * h + r) * 256 + j] = acc[mt][nt][r] + bb;
  }
}

// ---------------- launch ----------------
extern "C" void kernel_launch(void* const* d_in, const int* in_sizes, int n_in,
                              void* d_out, int out_size, void* d_ws, size_t ws_size,
                              hipStream_t stream) {
  const float* x  = (const float*)d_in[0];
  const float* Wq = (const float*)d_in[1];
  const float* bq = (const float*)d_in[2];
  const float* Wk = (const float*)d_in[3];
  const float* bk = (const float*)d_in[4];
  const float* Wv = (const float*)d_in[5];
  const float* bv = (const float*)d_in[6];
  const float* Wo = (const float*)d_in[7];
  const float* bo = (const float*)d_in[8];
  float* outp = (float*)d_out;

  char* ws = (char*)d_ws;
  const size_t SZ_QKV = 67108864;   // 64*256*2048 * 2B
  size_t off = 0;
  bf16* Qs   = (bf16*)(ws + off); off += SZ_QKV;
  bf16* Ks   = (bf16*)(ws + off); off += SZ_QKV;
  bf16* Vq   = (bf16*)(ws + off); off += SZ_QKV;   // written by k1 directly
  bf16* attn = (bf16*)(ws + off); off += 8388608;
  bf16* Wp   = (bf16*)(ws + off); off += 393216;   // qkv fragment packs
  bf16* Wk3  = (bf16*)(ws + off); off += 131072;   // k3 fragment pack
  float* biasp = (float*)(ws + off); off += 3072;
  if (ws_size < off) return;        // workspace too small: bail cleanly

  bf16* yhat = Qs;                  // Qs dead after k2a

  k0_prep<<<64, 256, 0, stream>>>(Wq, bq, Wk, bk, Wv, bv, Wo, Wp, Wk3, biasp);
  k1_qkv<<<1536, 512, 0, stream>>>(x, Wp, biasp, Qs, Ks, Vq);
  k2a_scores<<<128, 1024, 0, stream>>>(Qs, Ks, attn);
  k2b_pv<<<2048, 512, 0, stream>>>(attn, Vq, yhat);
  k3_out<<<2048, 512, 0, stream>>>(yhat, Wk3, bo, outp);
}

// Round 17
// 298.153 us; speedup vs baseline: 1.1565x; 1.1565x over previous
//
#include <hip/hip_runtime.h>
#include <hip/hip_bf16.h>

// MultiheadAttention_ViTNO: B=8, P=256, S=8x8(=64), D=256, NHEAD=8, DK=32, SCALE=64
// R17: full revert to R12 (R16's re-tiling caused partial-line Q/K stores:
// FETCH 2x, WRITE +70MB -> k1 170us). ONE isolated change vs R12:
// k2a grid 128 -> 256 (R15's kernel verbatim, which passed): p-quarter
// 64/block, 16 waves, 80KB dbuf LDS. R12's k2a had 1 block/CU on a 128-grid
// = HALF THE CHIP IDLE. (R15's regression attributed to k2b-persistent VGPR
// spill: 132 > 128 cap; its k2a was innocent.) All else R12 verbatim.

typedef __bf16 bf16;
typedef __attribute__((ext_vector_type(8))) __bf16 bf16x8;
typedef __attribute__((ext_vector_type(4))) float floatx4;
typedef __attribute__((ext_vector_type(8))) unsigned short ushort8;

#define CDIM 2048             // 64*32 flattened (sxy, dk) per head

static __device__ __forceinline__ floatx4 mfma16(bf16x8 a, bf16x8 b, floatx4 c) {
  return __builtin_amdgcn_mfma_f32_16x16x32_bf16(a, b, c, 0, 0, 0);
}

static __device__ __forceinline__ void gload_lds16(const void* g, void* l) {
  __builtin_amdgcn_global_load_lds((const __attribute__((address_space(1))) void*)g,
                                   (__attribute__((address_space(3))) void*)l, 16, 0, 0);
}

// ---------------- K0: weight prep (R12 verbatim) ----------------
__global__ __launch_bounds__(256) void k0_prep(
    const float* __restrict__ Wq, const float* __restrict__ bq,
    const float* __restrict__ Wk, const float* __restrict__ bk,
    const float* __restrict__ Wv, const float* __restrict__ bv,
    const float* __restrict__ Wo,
    bf16* __restrict__ Wp, bf16* __restrict__ Wk3, float* __restrict__ biasp)
{
  const int bid = blockIdx.x, tid = threadIdx.x;
  int g = (bid & 31) * 256 + tid;       // 0..8191 : (kk, rowblk, lane)
  int lane = g & 63, rowblk = (g >> 6) & 15, kk = g >> 10;
  int h = lane >> 4, cl = lane & 15;
  int d0 = kk * 32 + 8 * h;
  if (bid < 32) {
    int ip = rowblk * 16 + cl;          // i' = n*32+dk
    int isrc = ((ip & 31) << 3) | (ip >> 5);
#pragma unroll
    for (int mat = 0; mat < 3; mat++) {
      const float* W = (mat == 0) ? Wq : (mat == 1) ? Wk : Wv;
      bf16x8 v;
#pragma unroll
      for (int j = 0; j < 8; j++) v[j] = (bf16)W[isrc * 256 + d0 + j];
      *reinterpret_cast<bf16x8*>(Wp + ((size_t)mat * 8192 + g) * 8) = v;
    }
    if (bid == 0 && tid < 256) {
      int bs = ((tid & 31) << 3) | (tid >> 5);
      biasp[tid] = bq[bs]; biasp[256 + tid] = bk[bs]; biasp[512 + tid] = bv[bs];
    }
  } else {
    int j = rowblk * 16 + cl;           // output col
    bf16x8 v;
#pragma unroll
    for (int jj = 0; jj < 8; jj++) {
      int c = d0 + jj;
      v[jj] = (bf16)Wo[j * 256 + (((c & 31) << 3) | (c >> 5))];
    }
    *reinterpret_cast<bf16x8*>(Wk3 + (size_t)g * 8) = v;
  }
}

// ---------------- K1: fused QKV projection, pipelined persistent (R12) ----------
__global__ __launch_bounds__(512, 4) void k1_qkv(
    const float* __restrict__ x, const bf16* __restrict__ Wp,
    const float* __restrict__ biasp,
    bf16* __restrict__ Qs, bf16* __restrict__ Ks, bf16* __restrict__ Vt)
{
  __shared__ bf16 buf[2][64 * 256];     // 2 x 32KB, granule-XOR-swizzled
  const int bx = blockIdx.x;
  const int tid = threadIdx.x;
  const int lane = tid & 63;
  const int w = tid >> 6;               // wave 0..7 -> ip slice [w*32, w*32+32)
  const int h = lane >> 4, cl = lane & 15;
  const int c7 = cl & 7;

  floatx4 sreg[8];                      // 32 VGPR staging (one 64-token tile)

#define K1_LOAD(VB)                                                          \
  {                                                                          \
    int a_ = (VB) / 24;                                                      \
    int t0_ = (a_ * 8 + ((VB) & 7)) * 64;                                    \
    _Pragma("unroll")                                                        \
    for (int k = 0; k < 4; ++k) {                                            \
      int G = k * 512 + tid;                                                 \
      int row = G >> 5;                                                      \
      const float* sp = x + (size_t)(t0_ + row) * 256 + (G & 31) * 8;        \
      sreg[2 * k]     = *reinterpret_cast<const floatx4*>(sp);               \
      sreg[2 * k + 1] = *reinterpret_cast<const floatx4*>(sp + 4);           \
    }                                                                        \
  }

#define K1_CVTWRITE(BUFI)                                                    \
  {                                                                          \
    _Pragma("unroll")                                                        \
    for (int k = 0; k < 4; ++k) {                                            \
      int G = k * 512 + tid;                                                 \
      int row = G >> 5;                                                      \
      bf16x8 v;                                                              \
      _Pragma("unroll")                                                      \
      for (int j = 0; j < 4; j++) {                                          \
        v[j] = (bf16)sreg[2 * k][j];                                         \
        v[4 + j] = (bf16)sreg[2 * k + 1][j];                                 \
      }                                                                      \
      int Gp = (G & ~7) | ((G ^ row) & 7);                                   \
      *reinterpret_cast<bf16x8*>(&buf[BUFI][Gp * 8]) = v;                    \
    }                                                                        \
  }

#define K1_COMPUTE(VB, BUFI)                                                 \
  {                                                                          \
    int a_ = (VB) / 24;                                                      \
    int rem_ = (VB) - a_ * 24;                                               \
    int mat_ = rem_ >> 3;                                                    \
    int t0_ = (a_ * 8 + (rem_ & 7)) * 64;                                    \
    const bf16* Wm = Wp + (size_t)mat_ * 65536;                              \
    floatx4 acc[4][2];                                                       \
    _Pragma("unroll")                                                        \
    for (int i = 0; i < 4; i++)                                              \
      _Pragma("unroll")                                                      \
      for (int j = 0; j < 2; j++) acc[i][j] = (floatx4)0.0f;                 \
    _Pragma("unroll 2")                                                      \
    for (int kk = 0; kk < 8; ++kk) {                                         \
      bf16x8 av[4];                                                          \
      _Pragma("unroll")                                                      \
      for (int mt = 0; mt < 4; mt++) {                                       \
        int rr = mt * 16 + cl;                                               \
        int G = rr * 32 + kk * 4 + h;                                        \
        int Gp = (G & ~7) | ((G ^ c7) & 7);                                  \
        av[mt] = *reinterpret_cast<const bf16x8*>(&buf[BUFI][Gp * 8]);       \
      }                                                                      \
      bf16x8 b0 = *reinterpret_cast<const bf16x8*>(                          \
          Wm + ((size_t)(kk * 16 + w * 2 + 0) * 64 + lane) * 8);             \
      bf16x8 b1 = *reinterpret_cast<const bf16x8*>(                          \
          Wm + ((size_t)(kk * 16 + w * 2 + 1) * 64 + lane) * 8);             \
      _Pragma("unroll")                                                      \
      for (int mt = 0; mt < 4; mt++) acc[mt][0] = mfma16(av[mt], b0, acc[mt][0]); \
      _Pragma("unroll")                                                      \
      for (int mt = 0; mt < 4; mt++) acc[mt][1] = mfma16(av[mt], b1, acc[mt][1]); \
    }                                                                        \
    int b_ = t0_ >> 14;                                                      \
    int p_ = (t0_ >> 6) & 255;                                               \
    if (mat_ < 2) {                                                          \
      bf16* ob = ((mat_ == 0) ? Qs : Ks) + ((size_t)(b_ * 8 + w) * 256 + p_) * 2048; \
      _Pragma("unroll")                                                      \
      for (int nt = 0; nt < 2; nt++) {                                       \
        const int ip = w * 32 + nt * 16 + cl;                                \
        const float bb = biasp[mat_ * 256 + ip];                             \
        const int dk = nt * 16 + cl;                                         \
        _Pragma("unroll")                                                    \
        for (int mt = 0; mt < 4; mt++)                                       \
          _Pragma("unroll")                                                  \
          for (int r = 0; r < 4; r++) {                                      \
            int sxy = mt * 16 + 4 * h + r;                                   \
            ob[sxy * 32 + dk] = (bf16)(acc[mt][nt][r] + bb);                 \
          }                                                                  \
      }                                                                      \
    } else {                                                                 \
      _Pragma("unroll")                                                      \
      for (int nt = 0; nt < 2; nt++) {                                       \
        const int ip = w * 32 + nt * 16 + cl;                                \
        const float bb = biasp[512 + ip];                                    \
        _Pragma("unroll")                                                    \
        for (int mt = 0; mt < 4; mt++)                                       \
          _Pragma("unroll")                                                  \
          for (int r = 0; r < 4; r++) {                                      \
            int t = t0_ + mt * 16 + 4 * h + r;                               \
            Vt[(size_t)t * 256 + ip] = (bf16)(acc[mt][nt][r] + bb);          \
          }                                                                  \
      }                                                                      \
    }                                                                        \
  }

  K1_LOAD(bx);
  K1_CVTWRITE(0);
  __syncthreads();
#pragma unroll
  for (int u = 1; u < 4; ++u) {
    K1_LOAD(bx + u * 1536);
    K1_COMPUTE(bx + (u - 1) * 1536, (u - 1) & 1);
    __syncthreads();
    K1_CVTWRITE(u & 1);
    __syncthreads();
  }
  K1_COMPUTE(bx + 3 * 1536, 1);

#undef K1_LOAD
#undef K1_CVTWRITE
#undef K1_COMPUTE
}

// ---------------- K2a: scores + softmax (grid 256, full chip; R15 kernel) ------
// grid 256 = 64 bn (low bits) x 4 p-quarters of 64; block 1024 (16 waves,
// wr=p-slice 16 rows, wc=q-slice 64). Plain dbuf.
__global__ __launch_bounds__(1024, 1) void k2a_scores(
    const bf16* __restrict__ Qs, const bf16* __restrict__ Ks,
    bf16* __restrict__ attn)
{
  __shared__ bf16 Qch[2][64 * 64];      // 8KB x2
  __shared__ bf16 Kch[2][256 * 64];     // 32KB x2  (80KB total)
  __shared__ float redmax[4][4][16];
  __shared__ float redsum[4][4][16];

  const int bx = blockIdx.x;
  const int bn = bx & 63;
  const int p0 = (bx >> 6) * 64;
  const int tid = threadIdx.x;
  const int lane = tid & 63;
  const int w = tid >> 6;               // 0..15
  const int wr = w >> 2, wc = w & 3;
  const int h = lane >> 4, cl = lane & 15;

  const bf16* Qb = Qs + (size_t)bn * 524288 + (size_t)p0 * 2048;
  const bf16* Kb = Ks + (size_t)bn * 524288;

  // Q: 512 granules (64 rows x 8), staged by waves 0..7 (1 granule/thread)
  const int rq = tid >> 3, sq = (tid & 7) ^ (rq & 7);
  const size_t qsrc = (size_t)rq * 2048 + sq * 8;
  // K: 2048 granules, 2/thread
  int rk[2]; size_t ksrc[2];
#pragma unroll
  for (int i = 0; i < 2; ++i) {
    int L = i * 1024 + tid;
    rk[i] = L >> 3;
    int s = (L & 7) ^ (rk[i] & 7);
    ksrc[i] = (size_t)rk[i] * 2048 + s * 8;
  }

#define K2A_STAGE(bufi, c)                                                  \
  {                                                                         \
    if (tid < 512) gload_lds16(Qb + qsrc + (c) * 64, &Qch[bufi][(w * 64) * 8]); \
    gload_lds16(Kb + ksrc[0] + (c) * 64, &Kch[bufi][(w * 64) * 8]);         \
    gload_lds16(Kb + ksrc[1] + (c) * 64, &Kch[bufi][(1024 + w * 64) * 8]);  \
  }

  floatx4 acc[4];                       // [nt]; wave rows = wr*16 + 4h + r
#pragma unroll
  for (int j = 0; j < 4; j++) acc[j] = (floatx4)0.0f;

  K2A_STAGE(0, 0);
  __syncthreads();
  int buf = 0;
  for (int c = 0; c < 32; ++c) {
    if (c + 1 < 32) K2A_STAGE(buf ^ 1, c + 1);
#pragma unroll
    for (int kk = 0; kk < 2; ++kk) {
      bf16x8 av, bv[4];
      {
        int row = wr * 16 + cl;
        int gg = kk * 4 + h;
        av = *reinterpret_cast<const bf16x8*>(
            &Qch[buf][(row * 8 + (gg ^ (row & 7))) * 8]);
      }
#pragma unroll
      for (int nt = 0; nt < 4; nt++) {
        int row = wc * 64 + nt * 16 + cl;
        int gg = kk * 4 + h;
        bv[nt] = *reinterpret_cast<const bf16x8*>(
            &Kch[buf][(row * 8 + (gg ^ (row & 7))) * 8]);
      }
#pragma unroll
      for (int nt = 0; nt < 4; nt++) acc[nt] = mfma16(av, bv[nt], acc[nt]);
    }
    __syncthreads();
    buf ^= 1;
  }

  // softmax over q (rows local: wr*16 + 4h + r)
  float pm[4];
#pragma unroll
  for (int r = 0; r < 4; r++)
    pm[r] = fmaxf(fmaxf(acc[0][r], acc[1][r]), fmaxf(acc[2][r], acc[3][r]));
#pragma unroll
  for (int off = 1; off < 16; off <<= 1)
#pragma unroll
    for (int r = 0; r < 4; r++)
      pm[r] = fmaxf(pm[r], __shfl_xor(pm[r], off, 64));
  if (cl == 0) {
#pragma unroll
    for (int r = 0; r < 4; r++) redmax[wr][wc][4 * h + r] = pm[r];
  }
  __syncthreads();

  float gm[4], ps[4];
#pragma unroll
  for (int r = 0; r < 4; r++) {
    int row = 4 * h + r;
    gm[r] = fmaxf(fmaxf(redmax[wr][0][row], redmax[wr][1][row]),
                  fmaxf(redmax[wr][2][row], redmax[wr][3][row]));
    ps[r] = 0.0f;
  }
  const float KS = 1.44269504088896340736f / 64.0f;   // log2(e)/SCALE
#pragma unroll
  for (int nt = 0; nt < 4; nt++)
#pragma unroll
    for (int r = 0; r < 4; r++) {
      float e = exp2f((acc[nt][r] - gm[r]) * KS);
      acc[nt][r] = e;
      ps[r] += e;
    }
#pragma unroll
  for (int off = 1; off < 16; off <<= 1)
#pragma unroll
    for (int r = 0; r < 4; r++) ps[r] += __shfl_xor(ps[r], off, 64);
  if (cl == 0) {
#pragma unroll
    for (int r = 0; r < 4; r++) redsum[wr][wc][4 * h + r] = ps[r];
  }
  __syncthreads();

#pragma unroll
  for (int r = 0; r < 4; r++) {
    int row = 4 * h + r;
    float gs = (redsum[wr][0][row] + redsum[wr][1][row])
             + (redsum[wr][2][row] + redsum[wr][3][row]);
    ps[r] = 1.0f / gs;
  }
#pragma unroll
  for (int nt = 0; nt < 4; nt++) {
    int q = wc * 64 + nt * 16 + cl;
#pragma unroll
    for (int r = 0; r < 4; r++) {
      int row = p0 + wr * 16 + 4 * h + r;
      attn[(size_t)bn * 65536 + row * 256 + q] = (bf16)(acc[nt][r] * ps[r]);
    }
  }
#undef K2A_STAGE
}

// ---------------- K2t: V transpose (R12 verbatim) ----------------
__global__ __launch_bounds__(256) void k2t_transpose(
    const bf16* __restrict__ Vtok, bf16* __restrict__ Vq)
{
  const int bx = blockIdx.x;
  const int bn = bx & 63;
  const int r2 = bx >> 6;                  // 0..127
  const int q0 = (r2 & 3) * 64;
  const int c0 = (r2 >> 2) * 64;           // c = sxy*32 + dk
  const int b = bn >> 3, n = bn & 7;
  __shared__ unsigned short tile[64][65];
  const unsigned short* src = (const unsigned short*)Vtok;
  unsigned short* dst = (unsigned short*)Vq + (size_t)bn * 524288;
  {
    const int q = threadIdx.x >> 3;            // 0..31
    const int cj = (threadIdx.x & 7) * 8;
    const int c = c0 + cj;
    const int sxy = c >> 5, dk0 = c & 31;
#pragma unroll
    for (int it = 0; it < 2; ++it) {
      int qq = q + it * 32;
      size_t sa = (size_t)((b * 256 + q0 + qq) * 64 + sxy) * 256 + n * 32 + dk0;
      ushort8 s = *reinterpret_cast<const ushort8*>(src + sa);
#pragma unroll
      for (int j = 0; j < 8; j++) tile[qq][cj + j] = s[j];
    }
  }
  __syncthreads();
  {
    const int crow = threadIdx.x >> 2;         // 0..63
    const int qj = (threadIdx.x & 3) * 8;
#pragma unroll
    for (int it = 0; it < 2; ++it) {
      int qq = qj + it * 32;
      ushort8 sv;
#pragma unroll
      for (int j = 0; j < 8; j++) sv[j] = tile[qq + j][crow];
      *reinterpret_cast<ushort8*>(dst + (size_t)(c0 + crow) * 256 + q0 + qq) = sv;
    }
  }
}

// ---------------- K2b: O = attn @ V (R12 verbatim) ----------------
__global__ __launch_bounds__(512, 6) void k2b_pv(
    const bf16* __restrict__ attn, const bf16* __restrict__ Vq,
    bf16* __restrict__ yhat)
{
  __shared__ bf16 As[64 * 256];         // 32KB
  const int bx = blockIdx.x;
  const int bn = bx & 63;
  const int r2 = bx >> 6;               // 0..31
  const int p0 = (r2 & 3) * 64;
  const int c0 = (r2 >> 2) * 256;
  const int b = bn >> 3, n = bn & 7;
  const int tid = threadIdx.x;
  const int lane = tid & 63;
  const int w = tid >> 6;               // wave -> 32-c slice of ctile
  const int h = lane >> 4, cl = lane & 15;
  const int c7 = cl & 7;

  const bf16* Ab = attn + (size_t)bn * 65536 + (size_t)p0 * 256;
  const bf16* Vb = Vq + (size_t)bn * 524288;

#pragma unroll
  for (int i = 0; i < 4; ++i) {
    int L = (i * 8 + w) * 64 + lane;
    int S = (L & ~7) | ((L ^ (L >> 5)) & 7);
    gload_lds16(Ab + (size_t)S * 8, &As[(size_t)(i * 8 + w) * 64 * 8]);
  }
  __syncthreads();

  floatx4 acc[4][2];
#pragma unroll
  for (int i = 0; i < 4; i++)
#pragma unroll
    for (int j = 0; j < 2; j++) acc[i][j] = (floatx4)0.0f;

#pragma unroll 2
  for (int kk = 0; kk < 8; ++kk) {
    bf16x8 av[4];
#pragma unroll
    for (int mt = 0; mt < 4; mt++) {
      int rr = mt * 16 + cl;
      int G = rr * 32 + kk * 4 + h;
      int Gp = (G & ~7) | ((G ^ c7) & 7);
      av[mt] = *reinterpret_cast<const bf16x8*>(&As[Gp * 8]);
    }
    bf16x8 b0 = *reinterpret_cast<const bf16x8*>(
        Vb + (size_t)(c0 + w * 32 + cl) * 256 + kk * 32 + 8 * h);
    bf16x8 b1 = *reinterpret_cast<const bf16x8*>(
        Vb + (size_t)(c0 + w * 32 + 16 + cl) * 256 + kk * 32 + 8 * h);
#pragma unroll
    for (int mt = 0; mt < 4; mt++) acc[mt][0] = mfma16(av[mt], b0, acc[mt][0]);
#pragma unroll
    for (int mt = 0; mt < 4; mt++) acc[mt][1] = mfma16(av[mt], b1, acc[mt][1]);
  }

#pragma unroll
  for (int nt = 0; nt < 2; nt++) {
    const int cg = c0 + w * 32 + nt * 16 + cl;
    const int dk = cg & 31, sxy = cg >> 5;
#pragma unroll
    for (int mt = 0; mt < 4; mt++)
#pragma unroll
      for (int r = 0; r < 4; r++) {
        int p = p0 + mt * 16 + 4 * h + r;
        size_t t = (size_t)((b * 256 + p) * 64) + sxy;
        yhat[t * 256 + n * 32 + dk] = (bf16)acc[mt][nt][r];
      }
  }
}

// ---------------- K3: output projection (R12 verbatim) ----------------
__global__ __launch_bounds__(512, 6) void k3_out(
    const bf16* __restrict__ yhat, const bf16* __restrict__ Wk3,
    const float* __restrict__ bo, float* __restrict__ outp)
{
  __shared__ bf16 As[64 * 256];         // 32KB
  const int t0 = blockIdx.x * 64;
  const int tid = threadIdx.x;
  const int lane = tid & 63;
  const int w = tid >> 6;
  const int h = lane >> 4, cl = lane & 15;
  const int c7 = cl & 7;

  const bf16* Ab = yhat + (size_t)t0 * 256;

#pragma unroll
  for (int i = 0; i < 4; ++i) {
    int L = (i * 8 + w) * 64 + lane;
    int S = (L & ~7) | ((L ^ (L >> 5)) & 7);
    gload_lds16(Ab + (size_t)S * 8, &As[(size_t)(i * 8 + w) * 64 * 8]);
  }
  __syncthreads();

  floatx4 acc[4][2];
#pragma unroll
  for (int i = 0; i < 4; i++)
#pragma unroll
    for (int j = 0; j < 2; j++) acc[i][j] = (floatx4)0.0f;

#pragma unroll 2
  for (int kk = 0; kk < 8; ++kk) {
    bf16x8 av[4];
#pragma unroll
    for (int mt = 0; mt < 4; mt++) {
      int rr = mt * 16 + cl;
      int G = rr * 32 + kk * 4 + h;
      int Gp = (G & ~7) | ((G ^ c7) & 7);
      av[mt] = *reinterpret_cast<const bf16x8*>(&As[Gp * 8]);
    }
    bf16x8 b0 = *reinterpret_cast<const bf16x8*>(
        Wk3 + ((size_t)(kk * 16 + w * 2 + 0) * 64 + lane) * 8);
    bf16x8 b1 = *reinterpret_cast<const bf16x8*>(
        Wk3 + ((size_t)(kk * 16 + w * 2 + 1) * 64 + lane) * 8);
#pragma unroll
    for (int mt = 0; mt < 4; mt++) acc[mt][0] = mfma16(av[mt], b0, acc[mt][0]);
#pragma unroll
    for (int mt = 0; mt < 4; mt++) acc[mt][1] = mfma16(av[mt], b1, acc[mt][1]);
  }

#pragma unroll
  for (int nt = 0; nt < 2; nt++) {
    const int j = w * 32 + nt * 16 + cl;
    const float bb = bo[j];
#pragma unroll
    for (int mt = 0; mt < 4; mt++)
#pragma unroll
      for (int r = 0; r < 4; r++)
        outp[(size_t)(t0 + mt * 16 + 4 * h + r) * 256 + j] = acc[mt][nt][r] + bb;
  }
}

// ---------------- launch ----------------
extern "C" void kernel_launch(void* const* d_in, const int* in_sizes, int n_in,
                              void* d_out, int out_size, void* d_ws, size_t ws_size,
                              hipStream_t stream) {
  const float* x  = (const float*)d_in[0];
  const float* Wq = (const float*)d_in[1];
  const float* bq = (const float*)d_in[2];
  const float* Wk = (const float*)d_in[3];
  const float* bk = (const float*)d_in[4];
  const float* Wv = (const float*)d_in[5];
  const float* bv = (const float*)d_in[6];
  const float* Wo = (const float*)d_in[7];
  const float* bo = (const float*)d_in[8];
  float* outp = (float*)d_out;

  char* ws = (char*)d_ws;
  const size_t SZ_QKV = 67108864;   // 64*256*2048 * 2B
  size_t off = 0;
  bf16* Qs   = (bf16*)(ws + off); off += SZ_QKV;
  bf16* Ks   = (bf16*)(ws + off); off += SZ_QKV;
  bf16* Vtok = (bf16*)(ws + off); off += SZ_QKV;
  bf16* attn = (bf16*)(ws + off); off += 8388608;
  bf16* Wp   = (bf16*)(ws + off); off += 393216;   // qkv fragment packs
  bf16* Wk3  = (bf16*)(ws + off); off += 131072;   // k3 fragment pack
  float* biasp = (float*)(ws + off); off += 3072;
  if (ws_size < off) return;        // workspace too small: bail cleanly

  bf16* yhat = Qs;                  // Qs dead after k2a
  bf16* Vq   = Ks;                  // Ks dead after k2a (k2t runs after k2a)

  k0_prep<<<64, 256, 0, stream>>>(Wq, bq, Wk, bk, Wv, bv, Wo, Wp, Wk3, biasp);
  k1_qkv<<<1536, 512, 0, stream>>>(x, Wp, biasp, Qs, Ks, Vtok);
  k2a_scores<<<256, 1024, 0, stream>>>(Qs, Ks, attn);
  k2t_transpose<<<8192, 256, 0, stream>>>(Vtok, Vq);
  k2b_pv<<<2048, 512, 0, stream>>>(attn, Vq, yhat);
  k3_out<<<2048, 512, 0, stream>>>(yhat, Wk3, bo, outp);
}